// Round 6
// baseline (185.402 us; speedup 1.0000x reference)
//
#include <hip/hip_runtime.h>

typedef __bf16 bf16;
typedef __bf16 bf16x8 __attribute__((ext_vector_type(8)));
typedef float  f32x4  __attribute__((ext_vector_type(4)));

#define T_SEQ   2048
#define D_HEAD  64
#define NH      16
#define BH      32
#define C_EMB   1024
#define WS_STRIDE (BH * T_SEQ * D_HEAD)   // 4,194,304 elems per plane
#define XN (4096 * 1024)
#define WN (3072 * 1024)
#define WS_NEEDED ((size_t)(3 * WS_STRIDE + XN + WN) * 2)
#define CVT_GRID 3584

__device__ __forceinline__ bf16x8 cvt8(float4 a, float4 b) {
    bf16x8 r;
    r[0] = (__bf16)a.x; r[1] = (__bf16)a.y; r[2] = (__bf16)a.z; r[3] = (__bf16)a.w;
    r[4] = (__bf16)b.x; r[5] = (__bf16)b.y; r[6] = (__bf16)b.z; r[7] = (__bf16)b.w;
    return r;
}

__device__ __forceinline__ void gl_lds16(const bf16* g, bf16* l) {
    __builtin_amdgcn_global_load_lds(
        (const __attribute__((address_space(1))) unsigned int*)g,
        (__attribute__((address_space(3))) unsigned int*)l,
        16, 0, 0);
}

__device__ __forceinline__ unsigned pack_bf16(float a, float b) {
    union { __bf16 h[2]; unsigned u; } pk;
    pk.h[0] = (__bf16)a; pk.h[1] = (__bf16)b;
    return pk.u;
}

// ---------------------------------------------------------------------------
// Kernel 0: fp32 -> bf16 convert of x and W.
// ---------------------------------------------------------------------------
__global__ __launch_bounds__(256) void cvt_bf16(
    const float* __restrict__ x, const float* __restrict__ W,
    bf16* __restrict__ xb, bf16* __restrict__ wb)
{
    const int t = blockIdx.x * 256 + threadIdx.x;   // 917504 threads
    const float* src; bf16* dst; int base;
    if (t < XN / 8) { src = x; dst = xb; base = t * 8; }
    else           { src = W; dst = wb; base = (t - XN / 8) * 8; }
    float4 a = *(const float4*)(src + base);
    float4 b = *(const float4*)(src + base + 4);
    *(bf16x8*)(dst + base) = cvt8(a, b);
}

// ---------------------------------------------------------------------------
// Kernel 1: qkv = xb @ wb^T + b.  256x192 tile, BK=64, 8 waves (2Mx4N),
// grid 16x16 = 256 blocks. 4-phase double-buffered pipeline, counted
// s_waitcnt vmcnt(7). (unchanged this round)
// ---------------------------------------------------------------------------
#define LDA(d, qi) {                                                          \
    const bf16* abase_ = Sh + (d)*16384 + (qi)*8192 + (wm*64 + l15)*64;       \
    _Pragma("unroll")                                                         \
    for (int ii_ = 0; ii_ < 4; ii_++) {                                       \
        _Pragma("unroll")                                                     \
        for (int dk_ = 0; dk_ < 2; dk_++)                                     \
            aF[ii_][dk_] = *(const bf16x8*)(abase_ + ii_*1024                 \
                                            + (((dk_*4 + l4) ^ k7) * 8));     \
    }                                                                         \
}

#define LDB(d) {                                                              \
    const bf16* bbase_ = Sh + 32768 + (d)*12288 + (wn*48 + l15)*64;           \
    _Pragma("unroll")                                                         \
    for (int jj_ = 0; jj_ < 3; jj_++) {                                       \
        _Pragma("unroll")                                                     \
        for (int dk_ = 0; dk_ < 2; dk_++)                                     \
            bF[jj_][dk_] = *(const bf16x8*)(bbase_ + jj_*1024                 \
                                            + (((dk_*4 + l4) ^ k7) * 8));     \
    }                                                                         \
}

#define STA(d, qi, s, ko) gl_lds16(                                           \
    aSrc + (size_t)((qi)*64 + (s)*128) * 1024 + (ko),                         \
    Sh + (d)*16384 + (qi)*8192 + (s)*4096 + w*512)

#define STB(d, u, ko) gl_lds16(                                               \
    bSrc + (size_t)((u)*64) * 1024 + (ko),                                    \
    Sh + 32768 + (d)*12288 + w*512 + (u)*4096)

#define MMA2(qi, ja, jb) {                                                    \
    __builtin_amdgcn_s_setprio(1);                                            \
    _Pragma("unroll")                                                         \
    for (int dk_ = 0; dk_ < 2; dk_++) {                                       \
        _Pragma("unroll")                                                     \
        for (int ii_ = 0; ii_ < 4; ii_++) {                                   \
            acc[(qi)*4 + ii_][ja] = __builtin_amdgcn_mfma_f32_16x16x32_bf16(  \
                aF[ii_][dk_], bF[ja][dk_], acc[(qi)*4 + ii_][ja], 0, 0, 0);   \
            acc[(qi)*4 + ii_][jb] = __builtin_amdgcn_mfma_f32_16x16x32_bf16(  \
                aF[ii_][dk_], bF[jb][dk_], acc[(qi)*4 + ii_][jb], 0, 0, 0);   \
        }                                                                     \
    }                                                                         \
    __builtin_amdgcn_s_setprio(0);                                            \
}

#define MMA1(qi, ja) {                                                        \
    __builtin_amdgcn_s_setprio(1);                                            \
    _Pragma("unroll")                                                         \
    for (int dk_ = 0; dk_ < 2; dk_++) {                                       \
        _Pragma("unroll")                                                     \
        for (int ii_ = 0; ii_ < 4; ii_++)                                     \
            acc[(qi)*4 + ii_][ja] = __builtin_amdgcn_mfma_f32_16x16x32_bf16(  \
                aF[ii_][dk_], bF[ja][dk_], acc[(qi)*4 + ii_][ja], 0, 0, 0);   \
    }                                                                         \
    __builtin_amdgcn_s_setprio(0);                                            \
}

#define BAR   __builtin_amdgcn_s_barrier()
#define LGKM0 asm volatile("s_waitcnt lgkmcnt(0)" ::: "memory")

#define HALF(d, sk)                                                           \
    /* P0 */                                                                  \
    LDA(d, 0) LDB(d)                                                          \
    BAR; LGKM0;                                                               \
    MMA2(0, 0, 1)                                                             \
    BAR;                                                                      \
    /* P1: B + A-qi0 died at P0 */                                            \
    STB(d, 0, sk); STB(d, 1, sk); STB(d, 2, sk);                              \
    STA(d, 0, 0, sk); STA(d, 0, 1, sk);                                       \
    BAR;                                                                      \
    MMA1(0, 2)                                                                \
    BAR;                                                                      \
    /* P2 */                                                                  \
    LDA(d, 1)                                                                 \
    BAR; LGKM0;                                                               \
    MMA2(1, 0, 1)                                                             \
    BAR;                                                                      \
    /* P3: A-qi1 died at P2 */                                                \
    STA(d, 1, 0, sk); STA(d, 1, 1, sk);                                       \
    BAR;                                                                      \
    MMA1(1, 2)                                                                \
    asm volatile("s_waitcnt vmcnt(7)" ::: "memory");                          \
    BAR;

__global__ __launch_bounds__(512, 2) void qkv_gemm4(
    const bf16* __restrict__ xb, const bf16* __restrict__ wb,
    const float* __restrict__ bias, bf16* __restrict__ ws)
{
    __shared__ bf16 Sh[65536];   // A: 2x32KB, B: 2x24KB (112KB); epi slices

    const int tid  = threadIdx.x;
    const int lane = tid & 63;
    const int w    = tid >> 6;            // 0..7
    const int wm   = w >> 2, wn = w & 3;  // 2x4 wave grid
    const int l15  = lane & 15, l4 = lane >> 4;
    const int k7   = l15 & 7;
    const int l8   = lane >> 3;           // staging row-in-wave
    const int csw  = (lane & 7) ^ l8;     // pre-swizzled source chunk

    const int swz = (blockIdx.x & 7) * 32 + (blockIdx.x >> 3);  // T1, bijective
    const int bm  = swz >> 4, bn = swz & 15;

    const bf16* aSrc = xb + (size_t)(bm * 256 + w * 8 + l8) * 1024 + csw * 8;
    const bf16* bSrc = wb + (size_t)(bn * 192 + w * 8 + l8) * 1024 + csw * 8;

    f32x4 acc[8][3];
#pragma unroll
    for (int i = 0; i < 8; i++)
#pragma unroll
        for (int j = 0; j < 3; j++) acc[i][j] = (f32x4){0.f, 0.f, 0.f, 0.f};

    bf16x8 aF[4][2], bF[3][2];

    // ---- prologue: stage tile0 -> buf0, tile1 -> buf1 (7 loads each) ----
    STA(0,0,0,0);  STA(0,0,1,0);  STA(0,1,0,0);  STA(0,1,1,0);
    STB(0,0,0);    STB(0,1,0);    STB(0,2,0);
    STA(1,0,0,64); STA(1,0,1,64); STA(1,1,0,64); STA(1,1,1,64);
    STB(1,0,64);   STB(1,1,64);   STB(1,2,64);
    asm volatile("s_waitcnt vmcnt(7)" ::: "memory");   // tile0 landed
    BAR;

    // ---- main loop: 8 iterations x 2 K-tiles (K=1024, BK=64) ----
    for (int it = 0; it < 8; ++it) {
        const int sk0 = (it < 7 ? (2 * it + 2) : 15) * 64;  // clamp: re-stage
        const int sk1 = (it < 7 ? (2 * it + 3) : 15) * 64;  // tile15 harmlessly
        HALF(0, sk0)
        HALF(1, sk1)
    }
    asm volatile("s_waitcnt vmcnt(0)" ::: "memory");   // drain garbage stages
    BAR;                                               // LDS now reusable

    // ---- epilogue: per-16-col-frag; +bias (+0.125 for q) ----
    float bv[3];
#pragma unroll
    for (int ff = 0; ff < 3; ff++)
        bv[ff] = bias[bn * 192 + wn * 48 + ff * 16 + l15];

    const int bi    = bm >> 3;                     // batch (block-uniform)
    const int tBase = (bm & 7) * 256 + wm * 128;   // t-offset of wave block
    bf16* Wl = Sh + w * 8192;                      // private 16 KiB slice
    bf16* vt = ws + 2 * (size_t)WS_STRIDE;

    // store phase: each frag 2048 elems in Wl
#pragma unroll
    for (int ff = 0; ff < 3; ff++) {
        const int col0 = bn * 192 + wn * 48 + ff * 16;
        const int wch  = col0 >> 10;               // plane (wave-uniform)
        const float qs = (wch == 0) ? 0.125f : 1.0f;
        if (wch < 2) {
            // [lt][16] layout, chunk-bit XOR on (lt)
#pragma unroll
            for (int i = 0; i < 8; i++)
#pragma unroll
                for (int r = 0; r < 4; r++) {
                    const int lt = i * 16 + l4 * 4 + r;
                    const int dl = l15;
                    Wl[ff * 2048 + lt * 16 + (((dl >> 3) ^ lt) & 1) * 8 + (dl & 7)]
                        = (__bf16)((acc[i][ff][r] + bv[ff]) * qs);
                }
        } else {
            // [dl][128] layout, 16-chunk XOR rotation on (ct ^ dl)
#pragma unroll
            for (int i = 0; i < 8; i++)
#pragma unroll
                for (int p = 0; p < 2; p++) {
                    const int lt0 = i * 16 + l4 * 4 + 2 * p;
                    const int ct  = lt0 >> 3;
                    const int dl  = l15;
                    *(unsigned*)&Wl[ff * 2048 + dl * 128
                                    + ((ct ^ dl) & 15) * 8 + (lt0 & 7)]
                        = pack_bf16(acc[i][ff][2 * p] + bv[ff],
                                    acc[i][ff][2 * p + 1] + bv[ff]);
                }
        }
    }
    __syncthreads();

    // readback + global store phase
#pragma unroll
    for (int ff = 0; ff < 3; ff++) {
        const int col0 = bn * 192 + wn * 48 + ff * 16;
        const int wch  = col0 >> 10;
        const int cc   = col0 & 1023;
        const int hh   = cc >> 6;
        const int dd0  = cc & 63;
        if (wch < 2) {
#pragma unroll
            for (int it = 0; it < 4; it++) {
                const int lt = it * 32 + (lane >> 1);
                const int c2 = lane & 1;
                bf16x8 v8 = *(const bf16x8*)&Wl[ff * 2048 + lt * 16
                                                + ((c2 ^ lt) & 1) * 8];
                *(bf16x8*)&ws[(size_t)wch * WS_STRIDE
                              + ((size_t)(bi * NH + hh) * T_SEQ + tBase + lt) * D_HEAD
                              + dd0 + c2 * 8] = v8;
            }
        } else {
#pragma unroll
            for (int e = 0; e < 4; e++) {
                const int dl = e * 4 + l4;
                const int ct = l15;
                bf16x8 v8 = *(const bf16x8*)&Wl[ff * 2048 + dl * 128
                                                + ((ct ^ dl) & 15) * 8];
                *(bf16x8*)&vt[((size_t)(bi * NH + hh) * D_HEAD + dd0 + dl) * T_SEQ
                              + tBase + ct * 8] = v8;
            }
        }
    }
}

// ---------------------------------------------------------------------------
// Kernel 1 fallback (ws too small): register-convert GEMM, scalar epilogue.
// ---------------------------------------------------------------------------
__global__ __launch_bounds__(256) void qkv_gemm(
    const float* __restrict__ x, const float* __restrict__ W,
    const float* __restrict__ bias, bf16* __restrict__ ws)
{
    __shared__ bf16 As[128 * 40];
    __shared__ bf16 Bs[128 * 40];

    const int tid  = threadIdx.x;
    const int lane = tid & 63;
    const int w    = tid >> 6;
    const int wm   = w >> 1, wn = w & 1;
    const int l15  = lane & 15, l4 = lane >> 4;
    const int bm   = blockIdx.x / 24, bn = blockIdx.x % 24;

    const int srow = tid >> 1;
    const int scol = (tid & 1) * 16;
    const float* xg = x + (size_t)(bm * 128 + srow) * 1024 + scol;
    const float* wg = W + (size_t)(bn * 128 + srow) * 1024 + scol;
    bf16* asw = &As[srow * 40 + scol];
    bf16* bsw = &Bs[srow * 40 + scol];

    f32x4 acc[4][4];
#pragma unroll
    for (int i = 0; i < 4; i++)
#pragma unroll
        for (int j = 0; j < 4; j++) acc[i][j] = (f32x4){0.f, 0.f, 0.f, 0.f};

    float bv[4];
#pragma unroll
    for (int j = 0; j < 4; j++) bv[j] = bias[bn * 128 + wn * 64 + j * 16 + l15];

    for (int kk = 0; kk < 32; ++kk) {
        const float* xp = xg + kk * 32;
        const float* wp = wg + kk * 32;
        float4 a0 = *(const float4*)(xp + 0);
        float4 a1 = *(const float4*)(xp + 4);
        float4 a2 = *(const float4*)(xp + 8);
        float4 a3 = *(const float4*)(xp + 12);
        float4 b0 = *(const float4*)(wp + 0);
        float4 b1 = *(const float4*)(wp + 4);
        float4 b2 = *(const float4*)(wp + 8);
        float4 b3 = *(const float4*)(wp + 12);

        __syncthreads();
        *(bf16x8*)(asw + 0) = cvt8(a0, a1);
        *(bf16x8*)(asw + 8) = cvt8(a2, a3);
        *(bf16x8*)(bsw + 0) = cvt8(b0, b1);
        *(bf16x8*)(bsw + 8) = cvt8(b2, b3);
        __syncthreads();

        bf16x8 aF[4], bF[4];
#pragma unroll
        for (int s = 0; s < 4; s++) {
            aF[s] = *(const bf16x8*)&As[(wm * 64 + s * 16 + l15) * 40 + l4 * 8];
            bF[s] = *(const bf16x8*)&Bs[(wn * 64 + s * 16 + l15) * 40 + l4 * 8];
        }
#pragma unroll
        for (int i = 0; i < 4; i++)
#pragma unroll
            for (int j = 0; j < 4; j++)
                acc[i][j] = __builtin_amdgcn_mfma_f32_16x16x32_bf16(
                    aF[i], bF[j], acc[i][j], 0, 0, 0);
    }

#pragma unroll
    for (int i = 0; i < 4; i++) {
#pragma unroll
        for (int j = 0; j < 4; j++) {
            const int n     = bn * 128 + wn * 64 + j * 16 + l15;
            const int which = n >> 10;
            const int cc    = n & 1023;
            const int h     = cc >> 6, d = cc & 63;
            const float qs  = (which == 0) ? 0.125f : 1.0f;
#pragma unroll
            for (int r = 0; r < 4; r++) {
                const int m  = bm * 128 + wm * 64 + i * 16 + l4 * 4 + r;
                const int bi = m >> 11, t = m & 2047;
                const int bh = bi * NH + h;
                const float v = (acc[i][j][r] + bv[j]) * qs;
                size_t idx;
                if (which == 2)
                    idx = 2 * (size_t)WS_STRIDE + ((size_t)bh * D_HEAD + d) * T_SEQ + t;
                else
                    idx = (size_t)which * WS_STRIDE + ((size_t)bh * T_SEQ + t) * D_HEAD + d;
                ws[idx] = (__bf16)v;
            }
        }
    }
}

// ---------------------------------------------------------------------------
// Kernel 2: causal ReLU attention v9 — LDS-free, barrier-free.
// 2048 blocks x 64 threads (1 wave each); 8 blocks/CU = 2 waves/SIMD, ALL
// active (v8's idle-wave problem gone). Each wave owns 32 q-rows of one
// q-tile and loads K/V MFMA fragments DIRECTLY global->register (16B/lane,
// same fragment contents as the verified v8 LDS reads) — zero LDS, zero
// s_barrier, zero inter-wave coupling. Software pipeline (compiler-managed
// waits): VLOAD(jt) flies under QK+pack; KLOAD(jt+1) issued before PV
// flies under PV + next VLOAD. Registers: kA 64 + vv 64 + PK 32 + o 32 +
// qF 16 (~230 total, 2 waves/SIMD). Grid order: qt descending (big waves
// dispatch first, tail-balanced); blk&31 = bh keeps each bh's 64 blocks on
// one XCD (4 bh x 512KB = 2MB <= 4MB L2).
// ---------------------------------------------------------------------------
#define KLOAD(jt_) {                                                          \
    const bf16* kb_ = kg + (size_t)(jt_) * 8192 + kOff;                       \
    _Pragma("unroll")                                                         \
    for (int m_ = 0; m_ < 4; m_++)                                            \
        _Pragma("unroll")                                                     \
        for (int h_ = 0; h_ < 2; h_++)                                        \
            _Pragma("unroll")                                                 \
            for (int d_ = 0; d_ < 2; d_++)                                    \
                kA[m_][h_][d_] = *(const bf16x8*)(kb_ + m_ * 2048             \
                                                  + h_ * 256 + d_ * 32);      \
}

#define VLOAD(jt_) {                                                          \
    const bf16* vb_ = vt + vOff + (jt_) * 128;                                \
    _Pragma("unroll")                                                         \
    for (int s_ = 0; s_ < 4; s_++)                                            \
        _Pragma("unroll")                                                     \
        for (int k_ = 0; k_ < 4; k_++)                                        \
            vv[s_][k_] = *(const bf16x8*)(vb_ + s_ * 32768 + k_ * 32);        \
}

__global__ __launch_bounds__(64) void attn(
    const bf16* __restrict__ ws, float* __restrict__ out)
{
    const int lane = threadIdx.x & 63;
    const int l15  = lane & 15, qd = lane >> 4;

    const int bh = blockIdx.x & 31;          // XCD = blk&7 = bh&7 affinity
    const int u  = blockIdx.x >> 5;          // 0..63
    const int qt = 15 - (u & 15);            // big q-tiles dispatch first
    const int rg = u >> 4;                   // 0..3: 32-row group in q-tile
    const int nj = qt + 1;
    const int qb = qt * 128;

    const bf16* qg = ws + (size_t)bh * (T_SEQ * D_HEAD);
    const bf16* kg = ws + WS_STRIDE + (size_t)bh * (T_SEQ * D_HEAD);
    const bf16* vt = ws + 2 * (size_t)WS_STRIDE + (size_t)bh * (D_HEAD * T_SEQ);
    const int b = bh >> 4, h = bh & 15;

    // per-lane fragment base offsets (elems)
    const int kOff = (8 * (l15 >> 2) + (l15 & 3)) * 64 + qd * 8;
    const int vOff = l15 * 2048 + qd * 8;    // d rows stride T_SEQ

    // Q fragments (pre-scaled by 1/8), live across whole loop
    bf16x8 qF[2][2];
#pragma unroll
    for (int sm = 0; sm < 2; sm++)
#pragma unroll
        for (int dk = 0; dk < 2; dk++)
            qF[sm][dk] = *(const bf16x8*)(qg
                + (qb + rg * 32 + sm * 16 + l15) * 64 + dk * 32 + qd * 8);

    f32x4 o[2][4];
#pragma unroll
    for (int sm = 0; sm < 2; sm++)
#pragma unroll
        for (int sd = 0; sd < 4; sd++) o[sm][sd] = (f32x4){0.f, 0.f, 0.f, 0.f};

    bf16x8 kA[4][2][2];   // K(jt) fragments: [m][h2][dk]
    bf16x8 vv[4][4];      // V(jt) fragments: [sd][kk]

    KLOAD(0);

    for (int jt = 0; jt < nj; ++jt) {
        VLOAD(jt);                       // flies under QK + pack

        // ---- QK (permuted rows) + relu + mask + pack ----
        const bool need_mask = (jt == nj - 1);
        unsigned PK[2][8][2];
#pragma unroll
        for (int m = 0; m < 4; m++) {
#pragma unroll
            for (int h2 = 0; h2 < 2; h2++) {
                f32x4 s0 = {0.f, 0.f, 0.f, 0.f}, s1 = {0.f, 0.f, 0.f, 0.f};
                __builtin_amdgcn_s_setprio(1);
                s0 = __builtin_amdgcn_mfma_f32_16x16x32_bf16(kA[m][h2][0], qF[0][0], s0, 0, 0, 0);
                s0 = __builtin_amdgcn_mfma_f32_16x16x32_bf16(kA[m][h2][1], qF[0][1], s0, 0, 0, 0);
                s1 = __builtin_amdgcn_mfma_f32_16x16x32_bf16(kA[m][h2][0], qF[1][0], s1, 0, 0, 0);
                s1 = __builtin_amdgcn_mfma_f32_16x16x32_bf16(kA[m][h2][1], qF[1][1], s1, 0, 0, 0);
                __builtin_amdgcn_s_setprio(0);
                const int keyb = jt * 128 + 32 * m + 8 * qd + 4 * h2;
                const int kn = 2 * m + h2;
#pragma unroll
                for (int sm = 0; sm < 2; sm++) {
                    const f32x4 sv = sm ? s1 : s0;
                    float v[4];
#pragma unroll
                    for (int r = 0; r < 4; r++) v[r] = fmaxf(sv[r], 0.f);
                    if (need_mask) {   // wave-uniform: last step only
                        const int q = qb + rg * 32 + sm * 16 + l15;
#pragma unroll
                        for (int r = 0; r < 4; r++)
                            if (q < keyb + r) v[r] = 0.f;
                    }
                    PK[sm][kn][0] = pack_bf16(v[0], v[1]);
                    PK[sm][kn][1] = pack_bf16(v[2], v[3]);
                }
            }
        }

        if (jt + 1 < nj) KLOAD(jt + 1);  // kA dead after QK; flies under PV

        // ---- PV: pF from this lane's PK dwords; vf from registers ----
#pragma unroll
        for (int kk = 0; kk < 4; kk++) {
            bf16x8 pF[2];
#pragma unroll
            for (int sm = 0; sm < 2; sm++) {
                union { unsigned dw[4]; bf16x8 v; } uu;
                uu.dw[0] = PK[sm][2 * kk + 0][0];
                uu.dw[1] = PK[sm][2 * kk + 0][1];
                uu.dw[2] = PK[sm][2 * kk + 1][0];
                uu.dw[3] = PK[sm][2 * kk + 1][1];
                pF[sm] = uu.v;
            }
            __builtin_amdgcn_s_setprio(1);
#pragma unroll
            for (int sd = 0; sd < 4; sd++) {
                o[0][sd] = __builtin_amdgcn_mfma_f32_16x16x32_bf16(pF[0], vv[sd][kk], o[0][sd], 0, 0, 0);
                o[1][sd] = __builtin_amdgcn_mfma_f32_16x16x32_bf16(pF[1], vv[sd][kk], o[1][sd], 0, 0, 0);
            }
            __builtin_amdgcn_s_setprio(0);
        }
    }

    // ---- plain-store O (exclusive q-row ownership) ----
#pragma unroll
    for (int sm = 0; sm < 2; sm++)
#pragma unroll
        for (int sd = 0; sd < 4; sd++) {
            const int d = sd * 16 + l15;
#pragma unroll
            for (int r = 0; r < 4; r++) {
                const int t = qb + rg * 32 + sm * 16 + qd * 4 + r;
                out[((size_t)b * T_SEQ + t) * C_EMB + h * 64 + d] = o[sm][sd][r];
            }
        }
}

extern "C" void kernel_launch(void* const* d_in, const int* in_sizes, int n_in,
                              void* d_out, int out_size, void* d_ws, size_t ws_size,
                              hipStream_t stream) {
    const float* x    = (const float*)d_in[0];
    const float* W    = (const float*)d_in[1];
    const float* bias = (const float*)d_in[2];
    float* out        = (float*)d_out;
    bf16*  ws         = (bf16*)d_ws;

    if (ws_size >= WS_NEEDED) {
        bf16* xb = ws + 3 * (size_t)WS_STRIDE;
        bf16* wb = xb + XN;
        cvt_bf16<<<dim3(CVT_GRID), dim3(256), 0, stream>>>(x, W, xb, wb);
        qkv_gemm4<<<dim3(256), dim3(512), 0, stream>>>(xb, wb, bias, ws);
    } else {
        qkv_gemm<<<dim3(768), dim3(256), 0, stream>>>(x, W, bias, ws);
    }
    attn<<<dim3(2048), dim3(64), 0, stream>>>(ws, out);
}

// Round 7
// 140.137 us; speedup vs baseline: 1.3230x; 1.3230x over previous
//
#include <hip/hip_runtime.h>

typedef __bf16 bf16;
typedef __bf16 bf16x8 __attribute__((ext_vector_type(8)));
typedef float  f32x4  __attribute__((ext_vector_type(4)));

#define T_SEQ   2048
#define D_HEAD  64
#define NH      16
#define BH      32
#define C_EMB   1024
#define WS_STRIDE (BH * T_SEQ * D_HEAD)   // 4,194,304 elems per plane
#define XN (4096 * 1024)
#define WN (3072 * 1024)
#define WS_NEEDED ((size_t)(3 * WS_STRIDE + XN + WN) * 2)
#define CVT_GRID 3584

__device__ __forceinline__ bf16x8 cvt8(float4 a, float4 b) {
    bf16x8 r;
    r[0] = (__bf16)a.x; r[1] = (__bf16)a.y; r[2] = (__bf16)a.z; r[3] = (__bf16)a.w;
    r[4] = (__bf16)b.x; r[5] = (__bf16)b.y; r[6] = (__bf16)b.z; r[7] = (__bf16)b.w;
    return r;
}

__device__ __forceinline__ void gl_lds16(const bf16* g, bf16* l) {
    __builtin_amdgcn_global_load_lds(
        (const __attribute__((address_space(1))) unsigned int*)g,
        (__attribute__((address_space(3))) unsigned int*)l,
        16, 0, 0);
}

__device__ __forceinline__ unsigned pack_bf16(float a, float b) {
    union { __bf16 h[2]; unsigned u; } pk;
    pk.h[0] = (__bf16)a; pk.h[1] = (__bf16)b;
    return pk.u;
}

// ---------------------------------------------------------------------------
// Kernel 0: fp32 -> bf16 convert of x and W.
// ---------------------------------------------------------------------------
__global__ __launch_bounds__(256) void cvt_bf16(
    const float* __restrict__ x, const float* __restrict__ W,
    bf16* __restrict__ xb, bf16* __restrict__ wb)
{
    const int t = blockIdx.x * 256 + threadIdx.x;   // 917504 threads
    const float* src; bf16* dst; int base;
    if (t < XN / 8) { src = x; dst = xb; base = t * 8; }
    else           { src = W; dst = wb; base = (t - XN / 8) * 8; }
    float4 a = *(const float4*)(src + base);
    float4 b = *(const float4*)(src + base + 4);
    *(bf16x8*)(dst + base) = cvt8(a, b);
}

// ---------------------------------------------------------------------------
// Kernel 1: qkv = xb @ wb^T + b.  256x192 tile, BK=64, 8 waves (2Mx4N),
// grid 16x16 = 256 blocks. 4-phase double-buffered pipeline, counted
// s_waitcnt vmcnt(7). (unchanged this round)
// ---------------------------------------------------------------------------
#define LDA(d, qi) {                                                          \
    const bf16* abase_ = Sh + (d)*16384 + (qi)*8192 + (wm*64 + l15)*64;       \
    _Pragma("unroll")                                                         \
    for (int ii_ = 0; ii_ < 4; ii_++) {                                       \
        _Pragma("unroll")                                                     \
        for (int dk_ = 0; dk_ < 2; dk_++)                                     \
            aF[ii_][dk_] = *(const bf16x8*)(abase_ + ii_*1024                 \
                                            + (((dk_*4 + l4) ^ k7) * 8));     \
    }                                                                         \
}

#define LDB(d) {                                                              \
    const bf16* bbase_ = Sh + 32768 + (d)*12288 + (wn*48 + l15)*64;           \
    _Pragma("unroll")                                                         \
    for (int jj_ = 0; jj_ < 3; jj_++) {                                       \
        _Pragma("unroll")                                                     \
        for (int dk_ = 0; dk_ < 2; dk_++)                                     \
            bF[jj_][dk_] = *(const bf16x8*)(bbase_ + jj_*1024                 \
                                            + (((dk_*4 + l4) ^ k7) * 8));     \
    }                                                                         \
}

#define STA(d, qi, s, ko) gl_lds16(                                           \
    aSrc + (size_t)((qi)*64 + (s)*128) * 1024 + (ko),                         \
    Sh + (d)*16384 + (qi)*8192 + (s)*4096 + w*512)

#define STB(d, u, ko) gl_lds16(                                               \
    bSrc + (size_t)((u)*64) * 1024 + (ko),                                    \
    Sh + 32768 + (d)*12288 + w*512 + (u)*4096)

#define MMA2(qi, ja, jb) {                                                    \
    __builtin_amdgcn_s_setprio(1);                                            \
    _Pragma("unroll")                                                         \
    for (int dk_ = 0; dk_ < 2; dk_++) {                                       \
        _Pragma("unroll")                                                     \
        for (int ii_ = 0; ii_ < 4; ii_++) {                                   \
            acc[(qi)*4 + ii_][ja] = __builtin_amdgcn_mfma_f32_16x16x32_bf16(  \
                aF[ii_][dk_], bF[ja][dk_], acc[(qi)*4 + ii_][ja], 0, 0, 0);   \
            acc[(qi)*4 + ii_][jb] = __builtin_amdgcn_mfma_f32_16x16x32_bf16(  \
                aF[ii_][dk_], bF[jb][dk_], acc[(qi)*4 + ii_][jb], 0, 0, 0);   \
        }                                                                     \
    }                                                                         \
    __builtin_amdgcn_s_setprio(0);                                            \
}

#define MMA1(qi, ja) {                                                        \
    __builtin_amdgcn_s_setprio(1);                                            \
    _Pragma("unroll")                                                         \
    for (int dk_ = 0; dk_ < 2; dk_++) {                                       \
        _Pragma("unroll")                                                     \
        for (int ii_ = 0; ii_ < 4; ii_++)                                     \
            acc[(qi)*4 + ii_][ja] = __builtin_amdgcn_mfma_f32_16x16x32_bf16(  \
                aF[ii_][dk_], bF[ja][dk_], acc[(qi)*4 + ii_][ja], 0, 0, 0);   \
    }                                                                         \
    __builtin_amdgcn_s_setprio(0);                                            \
}

#define BAR   __builtin_amdgcn_s_barrier()
#define LGKM0 asm volatile("s_waitcnt lgkmcnt(0)" ::: "memory")

#define HALF(d, sk)                                                           \
    /* P0 */                                                                  \
    LDA(d, 0) LDB(d)                                                          \
    BAR; LGKM0;                                                               \
    MMA2(0, 0, 1)                                                             \
    BAR;                                                                      \
    /* P1: B + A-qi0 died at P0 */                                            \
    STB(d, 0, sk); STB(d, 1, sk); STB(d, 2, sk);                              \
    STA(d, 0, 0, sk); STA(d, 0, 1, sk);                                       \
    BAR;                                                                      \
    MMA1(0, 2)                                                                \
    BAR;                                                                      \
    /* P2 */                                                                  \
    LDA(d, 1)                                                                 \
    BAR; LGKM0;                                                               \
    MMA2(1, 0, 1)                                                             \
    BAR;                                                                      \
    /* P3: A-qi1 died at P2 */                                                \
    STA(d, 1, 0, sk); STA(d, 1, 1, sk);                                       \
    BAR;                                                                      \
    MMA1(1, 2)                                                                \
    asm volatile("s_waitcnt vmcnt(7)" ::: "memory");                          \
    BAR;

__global__ __launch_bounds__(512, 2) void qkv_gemm4(
    const bf16* __restrict__ xb, const bf16* __restrict__ wb,
    const float* __restrict__ bias, bf16* __restrict__ ws)
{
    __shared__ bf16 Sh[65536];   // A: 2x32KB, B: 2x24KB (112KB); epi slices

    const int tid  = threadIdx.x;
    const int lane = tid & 63;
    const int w    = tid >> 6;            // 0..7
    const int wm   = w >> 2, wn = w & 3;  // 2x4 wave grid
    const int l15  = lane & 15, l4 = lane >> 4;
    const int k7   = l15 & 7;
    const int l8   = lane >> 3;           // staging row-in-wave
    const int csw  = (lane & 7) ^ l8;     // pre-swizzled source chunk

    const int swz = (blockIdx.x & 7) * 32 + (blockIdx.x >> 3);  // T1, bijective
    const int bm  = swz >> 4, bn = swz & 15;

    const bf16* aSrc = xb + (size_t)(bm * 256 + w * 8 + l8) * 1024 + csw * 8;
    const bf16* bSrc = wb + (size_t)(bn * 192 + w * 8 + l8) * 1024 + csw * 8;

    f32x4 acc[8][3];
#pragma unroll
    for (int i = 0; i < 8; i++)
#pragma unroll
        for (int j = 0; j < 3; j++) acc[i][j] = (f32x4){0.f, 0.f, 0.f, 0.f};

    bf16x8 aF[4][2], bF[3][2];

    // ---- prologue: stage tile0 -> buf0, tile1 -> buf1 (7 loads each) ----
    STA(0,0,0,0);  STA(0,0,1,0);  STA(0,1,0,0);  STA(0,1,1,0);
    STB(0,0,0);    STB(0,1,0);    STB(0,2,0);
    STA(1,0,0,64); STA(1,0,1,64); STA(1,1,0,64); STA(1,1,1,64);
    STB(1,0,64);   STB(1,1,64);   STB(1,2,64);
    asm volatile("s_waitcnt vmcnt(7)" ::: "memory");   // tile0 landed
    BAR;

    // ---- main loop: 8 iterations x 2 K-tiles (K=1024, BK=64) ----
    for (int it = 0; it < 8; ++it) {
        const int sk0 = (it < 7 ? (2 * it + 2) : 15) * 64;  // clamp: re-stage
        const int sk1 = (it < 7 ? (2 * it + 3) : 15) * 64;  // tile15 harmlessly
        HALF(0, sk0)
        HALF(1, sk1)
    }
    asm volatile("s_waitcnt vmcnt(0)" ::: "memory");   // drain garbage stages
    BAR;                                               // LDS now reusable

    // ---- epilogue: per-16-col-frag; +bias (+0.125 for q) ----
    float bv[3];
#pragma unroll
    for (int ff = 0; ff < 3; ff++)
        bv[ff] = bias[bn * 192 + wn * 48 + ff * 16 + l15];

    const int bi    = bm >> 3;                     // batch (block-uniform)
    const int tBase = (bm & 7) * 256 + wm * 128;   // t-offset of wave block
    bf16* Wl = Sh + w * 8192;                      // private 16 KiB slice
    bf16* vt = ws + 2 * (size_t)WS_STRIDE;

    // store phase: each frag 2048 elems in Wl
#pragma unroll
    for (int ff = 0; ff < 3; ff++) {
        const int col0 = bn * 192 + wn * 48 + ff * 16;
        const int wch  = col0 >> 10;               // plane (wave-uniform)
        const float qs = (wch == 0) ? 0.125f : 1.0f;
        if (wch < 2) {
            // [lt][16] layout, chunk-bit XOR on (lt)
#pragma unroll
            for (int i = 0; i < 8; i++)
#pragma unroll
                for (int r = 0; r < 4; r++) {
                    const int lt = i * 16 + l4 * 4 + r;
                    const int dl = l15;
                    Wl[ff * 2048 + lt * 16 + (((dl >> 3) ^ lt) & 1) * 8 + (dl & 7)]
                        = (__bf16)((acc[i][ff][r] + bv[ff]) * qs);
                }
        } else {
            // [dl][128] layout, 16-chunk XOR rotation on (ct ^ dl)
#pragma unroll
            for (int i = 0; i < 8; i++)
#pragma unroll
                for (int p = 0; p < 2; p++) {
                    const int lt0 = i * 16 + l4 * 4 + 2 * p;
                    const int ct  = lt0 >> 3;
                    const int dl  = l15;
                    *(unsigned*)&Wl[ff * 2048 + dl * 128
                                    + ((ct ^ dl) & 15) * 8 + (lt0 & 7)]
                        = pack_bf16(acc[i][ff][2 * p] + bv[ff],
                                    acc[i][ff][2 * p + 1] + bv[ff]);
                }
        }
    }
    __syncthreads();

    // readback + global store phase
#pragma unroll
    for (int ff = 0; ff < 3; ff++) {
        const int col0 = bn * 192 + wn * 48 + ff * 16;
        const int wch  = col0 >> 10;
        const int cc   = col0 & 1023;
        const int hh   = cc >> 6;
        const int dd0  = cc & 63;
        if (wch < 2) {
#pragma unroll
            for (int it = 0; it < 4; it++) {
                const int lt = it * 32 + (lane >> 1);
                const int c2 = lane & 1;
                bf16x8 v8 = *(const bf16x8*)&Wl[ff * 2048 + lt * 16
                                                + ((c2 ^ lt) & 1) * 8];
                *(bf16x8*)&ws[(size_t)wch * WS_STRIDE
                              + ((size_t)(bi * NH + hh) * T_SEQ + tBase + lt) * D_HEAD
                              + dd0 + c2 * 8] = v8;
            }
        } else {
#pragma unroll
            for (int e = 0; e < 4; e++) {
                const int dl = e * 4 + l4;
                const int ct = l15;
                bf16x8 v8 = *(const bf16x8*)&Wl[ff * 2048 + dl * 128
                                                + ((ct ^ dl) & 15) * 8];
                *(bf16x8*)&vt[((size_t)(bi * NH + hh) * D_HEAD + dd0 + dl) * T_SEQ
                              + tBase + ct * 8] = v8;
            }
        }
    }
}

// ---------------------------------------------------------------------------
// Kernel 1 fallback (ws too small): register-convert GEMM, scalar epilogue.
// ---------------------------------------------------------------------------
__global__ __launch_bounds__(256) void qkv_gemm(
    const float* __restrict__ x, const float* __restrict__ W,
    const float* __restrict__ bias, bf16* __restrict__ ws)
{
    __shared__ bf16 As[128 * 40];
    __shared__ bf16 Bs[128 * 40];

    const int tid  = threadIdx.x;
    const int lane = tid & 63;
    const int w    = tid >> 6;
    const int wm   = w >> 1, wn = w & 1;
    const int l15  = lane & 15, l4 = lane >> 4;
    const int bm   = blockIdx.x / 24, bn = blockIdx.x % 24;

    const int srow = tid >> 1;
    const int scol = (tid & 1) * 16;
    const float* xg = x + (size_t)(bm * 128 + srow) * 1024 + scol;
    const float* wg = W + (size_t)(bn * 128 + srow) * 1024 + scol;
    bf16* asw = &As[srow * 40 + scol];
    bf16* bsw = &Bs[srow * 40 + scol];

    f32x4 acc[4][4];
#pragma unroll
    for (int i = 0; i < 4; i++)
#pragma unroll
        for (int j = 0; j < 4; j++) acc[i][j] = (f32x4){0.f, 0.f, 0.f, 0.f};

    float bv[4];
#pragma unroll
    for (int j = 0; j < 4; j++) bv[j] = bias[bn * 128 + wn * 64 + j * 16 + l15];

    for (int kk = 0; kk < 32; ++kk) {
        const float* xp = xg + kk * 32;
        const float* wp = wg + kk * 32;
        float4 a0 = *(const float4*)(xp + 0);
        float4 a1 = *(const float4*)(xp + 4);
        float4 a2 = *(const float4*)(xp + 8);
        float4 a3 = *(const float4*)(xp + 12);
        float4 b0 = *(const float4*)(wp + 0);
        float4 b1 = *(const float4*)(wp + 4);
        float4 b2 = *(const float4*)(wp + 8);
        float4 b3 = *(const float4*)(wp + 12);

        __syncthreads();
        *(bf16x8*)(asw + 0) = cvt8(a0, a1);
        *(bf16x8*)(asw + 8) = cvt8(a2, a3);
        *(bf16x8*)(bsw + 0) = cvt8(b0, b1);
        *(bf16x8*)(bsw + 8) = cvt8(b2, b3);
        __syncthreads();

        bf16x8 aF[4], bF[4];
#pragma unroll
        for (int s = 0; s < 4; s++) {
            aF[s] = *(const bf16x8*)&As[(wm * 64 + s * 16 + l15) * 40 + l4 * 8];
            bF[s] = *(const bf16x8*)&Bs[(wn * 64 + s * 16 + l15) * 40 + l4 * 8];
        }
#pragma unroll
        for (int i = 0; i < 4; i++)
#pragma unroll
            for (int j = 0; j < 4; j++)
                acc[i][j] = __builtin_amdgcn_mfma_f32_16x16x32_bf16(
                    aF[i], bF[j], acc[i][j], 0, 0, 0);
    }

#pragma unroll
    for (int i = 0; i < 4; i++) {
#pragma unroll
        for (int j = 0; j < 4; j++) {
            const int n     = bn * 128 + wn * 64 + j * 16 + l15;
            const int which = n >> 10;
            const int cc    = n & 1023;
            const int h     = cc >> 6, d = cc & 63;
            const float qs  = (which == 0) ? 0.125f : 1.0f;
#pragma unroll
            for (int r = 0; r < 4; r++) {
                const int m  = bm * 128 + wm * 64 + i * 16 + l4 * 4 + r;
                const int bi = m >> 11, t = m & 2047;
                const int bh = bi * NH + h;
                const float v = (acc[i][j][r] + bv[j]) * qs;
                size_t idx;
                if (which == 2)
                    idx = 2 * (size_t)WS_STRIDE + ((size_t)bh * D_HEAD + d) * T_SEQ + t;
                else
                    idx = (size_t)which * WS_STRIDE + ((size_t)bh * T_SEQ + t) * D_HEAD + d;
                ws[idx] = (__bf16)v;
            }
        }
    }
}

// ---------------------------------------------------------------------------
// Kernel 2: causal ReLU attention v10 — v7 machinery, max TLP.
// 1024 blocks x 256 threads (4 waves): block = (bh, qslice of 64 q-rows),
// each wave owns 16 q-rows. LDS 48 KB (K dbuf 2x16 + V 16) -> 3 blocks/CU
// resident = 12 waves/CU (v8 measured ~5; v9's 1/occupancy scaling says
// latency-bound time drops with resident waves). All staging/swizzle/
// counted-vmcnt machinery is v7's verbatim (correctness-proven R3):
//   K: stored pos = chunk ^ (row&7) ^ (((row>>3)&3)<<1), both sides
//   V: stored pos = chunk ^ (row&15), both sides
//   queue [K(jt)4, V(jt)4, K(jt+1)4]: vmcnt(8) retires K(jt); after QK
//   vmcnt(4) retires V(jt), K(jt+1) stays in flight.
// Work-descending dispatch (s = 31-u); diagonal-tile skip: even half-
// slices (hs==0) bound QK m-loop / PV kk-loop to 2 (upper 64 keys of the
// last tile are fully masked for them).
// ---------------------------------------------------------------------------
#define KSTAGE(jt_, p_) {                                                     \
    _Pragma("unroll")                                                         \
    for (int e_ = 0; e_ < 4; e_++) {                                          \
        const int rb_ = w * 32 + e_ * 8;                                      \
        gl_lds16(kg + (size_t)((jt_) * 128 + rb_ + ksub) * 64                 \
                    + ((kc ^ ksub ^ (e_ << 1)) * 8),                          \
                 &Kb[p_][rb_ * 64]);                                          \
    }                                                                         \
}

#define VSTAGE(jt_) {                                                         \
    _Pragma("unroll")                                                         \
    for (int e_ = 0; e_ < 4; e_++) {                                          \
        const int rb_ = w * 16 + e_ * 4;                                      \
        const int sw_ = (rb_ & 12) + vsub;   /* == (row & 15) */              \
        gl_lds16(vt + (size_t)(rb_ + vsub) * T_SEQ + (jt_) * 128              \
                    + ((vc ^ sw_) * 8),                                       \
                 &Vts[rb_ * 128]);                                            \
    }                                                                         \
}

__global__ __launch_bounds__(256) void attn(
    const bf16* __restrict__ ws, float* __restrict__ out)
{
    __shared__ bf16 Kb[2][128 * 64];   // [key][d], chunk ^ (r&7) ^ ((r>>3)&3)<<1
    __shared__ bf16 Vts[64 * 128];     // [d][key], 16-chunk XOR swizzle

    const int tid  = threadIdx.x;
    const int lane = tid & 63;
    const int w    = tid >> 6;           // 0..3
    const int l15  = lane & 15, qd = lane >> 4;

    const int bh = blockIdx.x & 31;      // XCD = blk&7 -> bh mod 8 affinity
    const int u  = blockIdx.x >> 5;      // 0..31
    const int s  = 31 - u;               // big q-slices dispatch first
    const int qt = s >> 1;               // q-tile 0..15
    const int hs = s & 1;                // half within q-tile
    const int nj = qt + 1;
    const int qb = s * 64;               // block q-row base

    const bf16* qg = ws + (size_t)bh * (T_SEQ * D_HEAD);
    const bf16* kg = ws + WS_STRIDE + (size_t)bh * (T_SEQ * D_HEAD);
    const bf16* vt = ws + 2 * (size_t)WS_STRIDE + (size_t)bh * (D_HEAD * T_SEQ);
    const int b = bh >> 4, h = bh & 15;

    // staging lane constants
    const int ksub = lane >> 3;          // K: row-in-issue 0..7
    const int kc   = lane & 7;           // K: stored chunk position
    const int vsub = qd;                 // V: row-in-issue 0..3
    const int vc   = l15;                // V: stored chunk position

    // K fragment-read lane constants (conflict-free positions)
    const int krow0 = 8 * (l15 >> 2) + (l15 & 3);                  // row base
    const int pos00 = qd ^ (l15 & 3) ^ ((l15 >> 2) << 1);          // 0..7
    const int kbO0  = krow0 * 64 + pos00 * 8;
    const int kbO1  = krow0 * 64 + (pos00 ^ 4) * 8;

    // Q fragments (pre-scaled by 1/8), live across whole loop
    bf16x8 qF[2];
#pragma unroll
    for (int dk = 0; dk < 2; dk++)
        qF[dk] = *(const bf16x8*)(qg
            + (qb + w * 16 + l15) * 64 + dk * 32 + qd * 8);

    f32x4 o[4];
#pragma unroll
    for (int sd = 0; sd < 4; sd++) o[sd] = (f32x4){0.f, 0.f, 0.f, 0.f};

    // ---- prologue: stage K tile 0 into buffer 0 ----
    KSTAGE(0, 0);

    for (int jt = 0; jt < nj; ++jt) {
        const int p = jt & 1;
        const bool more = (jt + 1 < nj);
        // V(jt) first (mid-step counted wait retires it), then K(jt+1).
        VSTAGE(jt);
        if (more) {
            KSTAGE(jt + 1, p ^ 1);
            asm volatile("s_waitcnt vmcnt(8)" ::: "memory");  // K(jt) landed
        } else {
            asm volatile("s_waitcnt vmcnt(4)" ::: "memory");  // K(jt) landed
        }
        BAR;   // K tile jt visible to all waves

        const bf16* kb0 = &Kb[p][kbO0];
        const bf16* kb1 = &Kb[p][kbO1];

        // ---- QK (permuted rows) + relu + mask + pack ----
        const bool need_mask = (jt == nj - 1);
        // diagonal tile, even half-slice: keys >= qt*128+64 fully masked
        const int mMax = (need_mask && hs == 0) ? 2 : 4;
        unsigned PK[8][2];
#pragma unroll
        for (int m = 0; m < 4; m++) {
            if (m < mMax) {
                bf16x8 kf[2][2];
                kf[0][0] = *(const bf16x8*)(kb0 + m * 2048);        // kn=2m, lo
                kf[0][1] = *(const bf16x8*)(kb1 + m * 2048);        // kn=2m, hi
                kf[1][0] = *(const bf16x8*)(kb1 + m * 2048 + 256);  // kn=2m+1, lo
                kf[1][1] = *(const bf16x8*)(kb0 + m * 2048 + 256);  // kn=2m+1, hi
#pragma unroll
                for (int h2 = 0; h2 < 2; h2++) {
                    const int kn = 2 * m + h2;
                    f32x4 s0 = {0.f, 0.f, 0.f, 0.f};
                    __builtin_amdgcn_s_setprio(1);
                    s0 = __builtin_amdgcn_mfma_f32_16x16x32_bf16(kf[h2][0], qF[0], s0, 0, 0, 0);
                    s0 = __builtin_amdgcn_mfma_f32_16x16x32_bf16(kf[h2][1], qF[1], s0, 0, 0, 0);
                    __builtin_amdgcn_s_setprio(0);
                    const int keyb = jt * 128 + 32 * m + 8 * qd + 4 * h2;
                    float v[4];
#pragma unroll
                    for (int r = 0; r < 4; r++) v[r] = fmaxf(s0[r], 0.f);
                    if (need_mask) {   // wave-uniform: last step only
                        const int q = qb + w * 16 + l15;
#pragma unroll
                        for (int r = 0; r < 4; r++)
                            if (q < keyb + r) v[r] = 0.f;
                    }
                    PK[kn][0] = pack_bf16(v[0], v[1]);
                    PK[kn][1] = pack_bf16(v[2], v[3]);
                }
            }
        }

        // V landed under QK; counted wait keeps K(jt+1) in flight
        if (more) asm volatile("s_waitcnt vmcnt(4)" ::: "memory");
        else      asm volatile("s_waitcnt vmcnt(0)" ::: "memory");
        BAR;   // V tile jt visible to all waves

        // ---- PV: pF direct from this lane's PK dwords; vF from LDS ----
#pragma unroll
        for (int kk = 0; kk < 4; kk++) {
            if (kk < mMax) {
                union { unsigned dw[4]; bf16x8 v; } uu;
                uu.dw[0] = PK[2 * kk + 0][0];
                uu.dw[1] = PK[2 * kk + 0][1];
                uu.dw[2] = PK[2 * kk + 1][0];
                uu.dw[3] = PK[2 * kk + 1][1];
                const bf16x8 pF = uu.v;
                __builtin_amdgcn_s_setprio(1);
#pragma unroll
                for (int sd = 0; sd < 4; sd++) {
                    bf16x8 vf = *(const bf16x8*)&Vts[(sd * 16 + l15) * 128
                                                     + (((kk * 4 + qd) ^ l15) * 8)];
                    o[sd] = __builtin_amdgcn_mfma_f32_16x16x32_bf16(pF, vf, o[sd], 0, 0, 0);
                }
                __builtin_amdgcn_s_setprio(0);
            }
        }

        BAR;   // WAR: next step's V/K staging overwrites buffers just read
    }

    // ---- plain-store O (exclusive q-row ownership) ----
#pragma unroll
    for (int sd = 0; sd < 4; sd++) {
        const int d = sd * 16 + l15;
#pragma unroll
        for (int r = 0; r < 4; r++) {
            const int t = qb + w * 16 + qd * 4 + r;
            out[((size_t)b * T_SEQ + t) * C_EMB + h * 64 + d] = o[sd][r];
        }
    }
}

extern "C" void kernel_launch(void* const* d_in, const int* in_sizes, int n_in,
                              void* d_out, int out_size, void* d_ws, size_t ws_size,
                              hipStream_t stream) {
    const float* x    = (const float*)d_in[0];
    const float* W    = (const float*)d_in[1];
    const float* bias = (const float*)d_in[2];
    float* out        = (float*)d_out;
    bf16*  ws         = (bf16*)d_ws;

    if (ws_size >= WS_NEEDED) {
        bf16* xb = ws + 3 * (size_t)WS_STRIDE;
        bf16* wb = xb + XN;
        cvt_bf16<<<dim3(CVT_GRID), dim3(256), 0, stream>>>(x, W, xb, wb);
        qkv_gemm4<<<dim3(256), dim3(512), 0, stream>>>(xb, wb, bias, ws);
    } else {
        qkv_gemm<<<dim3(768), dim3(256), 0, stream>>>(x, W, bias, ws);
    }
    attn<<<dim3(1024), dim3(256), 0, stream>>>(ws, out);
}

// Round 8
// 138.346 us; speedup vs baseline: 1.3401x; 1.0129x over previous
//
#include <hip/hip_runtime.h>

typedef __bf16 bf16;
typedef __bf16 bf16x8 __attribute__((ext_vector_type(8)));
typedef float  f32x4  __attribute__((ext_vector_type(4)));

#define T_SEQ   2048
#define D_HEAD  64
#define NH      16
#define BH      32
#define C_EMB   1024
#define WS_STRIDE (BH * T_SEQ * D_HEAD)   // 4,194,304 elems per plane
#define XN (4096 * 1024)
#define WN (3072 * 1024)
#define WS_NEEDED ((size_t)(3 * WS_STRIDE + XN + WN) * 2)
#define CVT_GRID 3584

__device__ __forceinline__ bf16x8 cvt8(float4 a, float4 b) {
    bf16x8 r;
    r[0] = (__bf16)a.x; r[1] = (__bf16)a.y; r[2] = (__bf16)a.z; r[3] = (__bf16)a.w;
    r[4] = (__bf16)b.x; r[5] = (__bf16)b.y; r[6] = (__bf16)b.z; r[7] = (__bf16)b.w;
    return r;
}

__device__ __forceinline__ void gl_lds16(const bf16* g, bf16* l) {
    __builtin_amdgcn_global_load_lds(
        (const __attribute__((address_space(1))) unsigned int*)g,
        (__attribute__((address_space(3))) unsigned int*)l,
        16, 0, 0);
}

__device__ __forceinline__ unsigned pack_bf16(float a, float b) {
    union { __bf16 h[2]; unsigned u; } pk;
    pk.h[0] = (__bf16)a; pk.h[1] = (__bf16)b;
    return pk.u;
}

// ---------------------------------------------------------------------------
// Kernel 0: fp32 -> bf16 convert of x and W.
// ---------------------------------------------------------------------------
__global__ __launch_bounds__(256) void cvt_bf16(
    const float* __restrict__ x, const float* __restrict__ W,
    bf16* __restrict__ xb, bf16* __restrict__ wb)
{
    const int t = blockIdx.x * 256 + threadIdx.x;   // 917504 threads
    const float* src; bf16* dst; int base;
    if (t < XN / 8) { src = x; dst = xb; base = t * 8; }
    else           { src = W; dst = wb; base = (t - XN / 8) * 8; }
    float4 a = *(const float4*)(src + base);
    float4 b = *(const float4*)(src + base + 4);
    *(bf16x8*)(dst + base) = cvt8(a, b);
}

// ---------------------------------------------------------------------------
// Kernel 1: qkv = xb @ wb^T + b.  128x192 tile, BK=64, 4 waves (1Mx4N),
// grid 32x16 = 512 blocks = 2 blocks/CU (80 KB LDS) -> 16 waves/CU, 2x the
// previous 1-block/CU residency: the second block's waves fill this block's
// barrier/vmcnt stalls (same occupancy mechanism just validated on attn).
// 4-phase double-buffered HALF schedule carried over; 10 global_load_lds
// per wave per K-tile (B: 6, A: 2+2), counted s_waitcnt vmcnt(10), never 0
// in the loop. Region deaths: B + A-qi0 die at P0 -> staged in P1; A-qi1
// dies at P2 -> staged in P3. LDS elems: A d*8192 + qi*4096 (2x16KB),
// B 16384 + d*12288 (2x24KB). Epilogue: per-wave 128x48, per-16-col frag,
// q/k via 128x16 transpose, v via 16x128 XOR-rotated transpose (verbatim
// from the 256x192 version with wm=0).
// ---------------------------------------------------------------------------
#define LDA(d, qi) {                                                          \
    const bf16* abase_ = Sh + (d)*8192 + (qi)*4096 + l15*64;                  \
    _Pragma("unroll")                                                         \
    for (int ii_ = 0; ii_ < 4; ii_++) {                                       \
        _Pragma("unroll")                                                     \
        for (int dk_ = 0; dk_ < 2; dk_++)                                     \
            aF[ii_][dk_] = *(const bf16x8*)(abase_ + ii_*1024                 \
                                            + (((dk_*4 + l4) ^ k7) * 8));     \
    }                                                                         \
}

#define LDB(d) {                                                              \
    const bf16* bbase_ = Sh + 16384 + (d)*12288 + (w*48 + l15)*64;            \
    _Pragma("unroll")                                                         \
    for (int jj_ = 0; jj_ < 3; jj_++) {                                       \
        _Pragma("unroll")                                                     \
        for (int dk_ = 0; dk_ < 2; dk_++)                                     \
            bF[jj_][dk_] = *(const bf16x8*)(bbase_ + jj_*1024                 \
                                            + (((dk_*4 + l4) ^ k7) * 8));     \
    }                                                                         \
}

#define STA(d, qi, s, ko) gl_lds16(                                           \
    aSrc + (size_t)((qi)*64 + (s)*32) * 1024 + (ko),                          \
    Sh + (d)*8192 + (qi)*4096 + (s)*2048 + w*512)

#define STB(d, u, ko) gl_lds16(                                               \
    bSrc + (size_t)((u)*32) * 1024 + (ko),                                    \
    Sh + 16384 + (d)*12288 + (u)*2048 + w*512)

#define MMA2(qi, ja, jb) {                                                    \
    __builtin_amdgcn_s_setprio(1);                                            \
    _Pragma("unroll")                                                         \
    for (int dk_ = 0; dk_ < 2; dk_++) {                                       \
        _Pragma("unroll")                                                     \
        for (int ii_ = 0; ii_ < 4; ii_++) {                                   \
            acc[(qi)*4 + ii_][ja] = __builtin_amdgcn_mfma_f32_16x16x32_bf16(  \
                aF[ii_][dk_], bF[ja][dk_], acc[(qi)*4 + ii_][ja], 0, 0, 0);   \
            acc[(qi)*4 + ii_][jb] = __builtin_amdgcn_mfma_f32_16x16x32_bf16(  \
                aF[ii_][dk_], bF[jb][dk_], acc[(qi)*4 + ii_][jb], 0, 0, 0);   \
        }                                                                     \
    }                                                                         \
    __builtin_amdgcn_s_setprio(0);                                            \
}

#define MMA1(qi, ja) {                                                        \
    __builtin_amdgcn_s_setprio(1);                                            \
    _Pragma("unroll")                                                         \
    for (int dk_ = 0; dk_ < 2; dk_++) {                                       \
        _Pragma("unroll")                                                     \
        for (int ii_ = 0; ii_ < 4; ii_++)                                     \
            acc[(qi)*4 + ii_][ja] = __builtin_amdgcn_mfma_f32_16x16x32_bf16(  \
                aF[ii_][dk_], bF[ja][dk_], acc[(qi)*4 + ii_][ja], 0, 0, 0);   \
    }                                                                         \
    __builtin_amdgcn_s_setprio(0);                                            \
}

#define BAR   __builtin_amdgcn_s_barrier()
#define LGKM0 asm volatile("s_waitcnt lgkmcnt(0)" ::: "memory")

// One K-tile (4 phases) on buffer d, staging tile t+2 at k-offset sk.
#define HALF(d, sk)                                                           \
    /* P0 */                                                                  \
    LDA(d, 0) LDB(d)                                                          \
    BAR; LGKM0;                                                               \
    MMA2(0, 0, 1)                                                             \
    BAR;                                                                      \
    /* P1: B + A-qi0 died at P0 */                                            \
    STB(d, 0, sk); STB(d, 1, sk); STB(d, 2, sk);                              \
    STB(d, 3, sk); STB(d, 4, sk); STB(d, 5, sk);                              \
    STA(d, 0, 0, sk); STA(d, 0, 1, sk);                                       \
    BAR;                                                                      \
    MMA1(0, 2)                                                                \
    BAR;                                                                      \
    /* P2 */                                                                  \
    LDA(d, 1)                                                                 \
    BAR; LGKM0;                                                               \
    MMA2(1, 0, 1)                                                             \
    BAR;                                                                      \
    /* P3: A-qi1 died at P2 */                                                \
    STA(d, 1, 0, sk); STA(d, 1, 1, sk);                                       \
    BAR;                                                                      \
    MMA1(1, 2)                                                                \
    asm volatile("s_waitcnt vmcnt(10)" ::: "memory");                         \
    BAR;

__global__ __launch_bounds__(256, 2) void qkv_gemm5(
    const bf16* __restrict__ xb, const bf16* __restrict__ wb,
    const float* __restrict__ bias, bf16* __restrict__ ws)
{
    __shared__ bf16 Sh[40960];   // A: 2x8192, B: 2x12288 elems (80 KiB)

    const int tid  = threadIdx.x;
    const int lane = tid & 63;
    const int w    = tid >> 6;            // 0..3 (N-split wave grid)
    const int l15  = lane & 15, l4 = lane >> 4;
    const int k7   = l15 & 7;
    const int l8   = lane >> 3;           // staging row-in-wave
    const int csw  = (lane & 7) ^ l8;     // pre-swizzled source chunk

    const int swz = (blockIdx.x & 7) * 64 + (blockIdx.x >> 3);  // T1, bijective
    const int bm  = swz >> 4, bn = swz & 15;   // bm 0..31, bn 0..15

    const bf16* aSrc = xb + (size_t)(bm * 128 + w * 8 + l8) * 1024 + csw * 8;
    const bf16* bSrc = wb + (size_t)(bn * 192 + w * 8 + l8) * 1024 + csw * 8;

    f32x4 acc[8][3];
#pragma unroll
    for (int i = 0; i < 8; i++)
#pragma unroll
        for (int j = 0; j < 3; j++) acc[i][j] = (f32x4){0.f, 0.f, 0.f, 0.f};

    bf16x8 aF[4][2], bF[3][2];

    // ---- prologue: stage tile0 -> buf0, tile1 -> buf1 (10 loads each) ----
    STA(0,0,0,0);  STA(0,0,1,0);  STA(0,1,0,0);  STA(0,1,1,0);
    STB(0,0,0);    STB(0,1,0);    STB(0,2,0);
    STB(0,3,0);    STB(0,4,0);    STB(0,5,0);
    STA(1,0,0,64); STA(1,0,1,64); STA(1,1,0,64); STA(1,1,1,64);
    STB(1,0,64);   STB(1,1,64);   STB(1,2,64);
    STB(1,3,64);   STB(1,4,64);   STB(1,5,64);
    asm volatile("s_waitcnt vmcnt(10)" ::: "memory");   // tile0 landed
    BAR;

    // ---- main loop: 8 iterations x 2 K-tiles (K=1024, BK=64) ----
    for (int it = 0; it < 8; ++it) {
        const int sk0 = (it < 7 ? (2 * it + 2) : 15) * 64;  // clamp: re-stage
        const int sk1 = (it < 7 ? (2 * it + 3) : 15) * 64;  // tile15 harmlessly
        HALF(0, sk0)
        HALF(1, sk1)
    }
    asm volatile("s_waitcnt vmcnt(0)" ::: "memory");   // drain garbage stages
    BAR;                                               // LDS now reusable

    // ---- epilogue: per-16-col-frag; +bias (+0.125 for q) ----
    float bv[3];
#pragma unroll
    for (int ff = 0; ff < 3; ff++)
        bv[ff] = bias[bn * 192 + w * 48 + ff * 16 + l15];

    const int bi    = bm >> 4;                     // batch (block-uniform)
    const int tBase = (bm & 15) * 128;             // t-offset of block
    bf16* Wl = Sh + w * 8192;                      // private 16 KiB slice
    bf16* vt = ws + 2 * (size_t)WS_STRIDE;

    // store phase: each frag 2048 elems in Wl
#pragma unroll
    for (int ff = 0; ff < 3; ff++) {
        const int col0 = bn * 192 + w * 48 + ff * 16;
        const int wch  = col0 >> 10;               // plane (wave-uniform)
        const float qs = (wch == 0) ? 0.125f : 1.0f;
        if (wch < 2) {
            // [lt][16] layout, chunk-bit XOR on (lt)
#pragma unroll
            for (int i = 0; i < 8; i++)
#pragma unroll
                for (int r = 0; r < 4; r++) {
                    const int lt = i * 16 + l4 * 4 + r;
                    const int dl = l15;
                    Wl[ff * 2048 + lt * 16 + (((dl >> 3) ^ lt) & 1) * 8 + (dl & 7)]
                        = (__bf16)((acc[i][ff][r] + bv[ff]) * qs);
                }
        } else {
            // [dl][128] layout, 16-chunk XOR rotation on (ct ^ dl)
#pragma unroll
            for (int i = 0; i < 8; i++)
#pragma unroll
                for (int p = 0; p < 2; p++) {
                    const int lt0 = i * 16 + l4 * 4 + 2 * p;
                    const int ct  = lt0 >> 3;
                    const int dl  = l15;
                    *(unsigned*)&Wl[ff * 2048 + dl * 128
                                    + ((ct ^ dl) & 15) * 8 + (lt0 & 7)]
                        = pack_bf16(acc[i][ff][2 * p] + bv[ff],
                                    acc[i][ff][2 * p + 1] + bv[ff]);
                }
        }
    }
    __syncthreads();

    // readback + global store phase
#pragma unroll
    for (int ff = 0; ff < 3; ff++) {
        const int col0 = bn * 192 + w * 48 + ff * 16;
        const int wch  = col0 >> 10;
        const int cc   = col0 & 1023;
        const int hh   = cc >> 6;
        const int dd0  = cc & 63;
        if (wch < 2) {
#pragma unroll
            for (int it = 0; it < 4; it++) {
                const int lt = it * 32 + (lane >> 1);
                const int c2 = lane & 1;
                bf16x8 v8 = *(const bf16x8*)&Wl[ff * 2048 + lt * 16
                                                + ((c2 ^ lt) & 1) * 8];
                *(bf16x8*)&ws[(size_t)wch * WS_STRIDE
                              + ((size_t)(bi * NH + hh) * T_SEQ + tBase + lt) * D_HEAD
                              + dd0 + c2 * 8] = v8;
            }
        } else {
#pragma unroll
            for (int e = 0; e < 4; e++) {
                const int dl = e * 4 + l4;
                const int ct = l15;
                bf16x8 v8 = *(const bf16x8*)&Wl[ff * 2048 + dl * 128
                                                + ((ct ^ dl) & 15) * 8];
                *(bf16x8*)&vt[((size_t)(bi * NH + hh) * D_HEAD + dd0 + dl) * T_SEQ
                              + tBase + ct * 8] = v8;
            }
        }
    }
}

// ---------------------------------------------------------------------------
// Kernel 1 fallback (ws too small): register-convert GEMM, scalar epilogue.
// ---------------------------------------------------------------------------
__global__ __launch_bounds__(256) void qkv_gemm(
    const float* __restrict__ x, const float* __restrict__ W,
    const float* __restrict__ bias, bf16* __restrict__ ws)
{
    __shared__ bf16 As[128 * 40];
    __shared__ bf16 Bs[128 * 40];

    const int tid  = threadIdx.x;
    const int lane = tid & 63;
    const int w    = tid >> 6;
    const int wm   = w >> 1, wn = w & 1;
    const int l15  = lane & 15, l4 = lane >> 4;
    const int bm   = blockIdx.x / 24, bn = blockIdx.x % 24;

    const int srow = tid >> 1;
    const int scol = (tid & 1) * 16;
    const float* xg = x + (size_t)(bm * 128 + srow) * 1024 + scol;
    const float* wg = W + (size_t)(bn * 128 + srow) * 1024 + scol;
    bf16* asw = &As[srow * 40 + scol];
    bf16* bsw = &Bs[srow * 40 + scol];

    f32x4 acc[4][4];
#pragma unroll
    for (int i = 0; i < 4; i++)
#pragma unroll
        for (int j = 0; j < 4; j++) acc[i][j] = (f32x4){0.f, 0.f, 0.f, 0.f};

    float bv[4];
#pragma unroll
    for (int j = 0; j < 4; j++) bv[j] = bias[bn * 128 + wn * 64 + j * 16 + l15];

    for (int kk = 0; kk < 32; ++kk) {
        const float* xp = xg + kk * 32;
        const float* wp = wg + kk * 32;
        float4 a0 = *(const float4*)(xp + 0);
        float4 a1 = *(const float4*)(xp + 4);
        float4 a2 = *(const float4*)(xp + 8);
        float4 a3 = *(const float4*)(xp + 12);
        float4 b0 = *(const float4*)(wp + 0);
        float4 b1 = *(const float4*)(wp + 4);
        float4 b2 = *(const float4*)(wp + 8);
        float4 b3 = *(const float4*)(wp + 12);

        __syncthreads();
        *(bf16x8*)(asw + 0) = cvt8(a0, a1);
        *(bf16x8*)(asw + 8) = cvt8(a2, a3);
        *(bf16x8*)(bsw + 0) = cvt8(b0, b1);
        *(bf16x8*)(bsw + 8) = cvt8(b2, b3);
        __syncthreads();

        bf16x8 aF[4], bF[4];
#pragma unroll
        for (int s = 0; s < 4; s++) {
            aF[s] = *(const bf16x8*)&As[(wm * 64 + s * 16 + l15) * 40 + l4 * 8];
            bF[s] = *(const bf16x8*)&Bs[(wn * 64 + s * 16 + l15) * 40 + l4 * 8];
        }
#pragma unroll
        for (int i = 0; i < 4; i++)
#pragma unroll
            for (int j = 0; j < 4; j++)
                acc[i][j] = __builtin_amdgcn_mfma_f32_16x16x32_bf16(
                    aF[i], bF[j], acc[i][j], 0, 0, 0);
    }

#pragma unroll
    for (int i = 0; i < 4; i++) {
#pragma unroll
        for (int j = 0; j < 4; j++) {
            const int n     = bn * 128 + wn * 64 + j * 16 + l15;
            const int which = n >> 10;
            const int cc    = n & 1023;
            const int h     = cc >> 6, d = cc & 63;
            const float qs  = (which == 0) ? 0.125f : 1.0f;
#pragma unroll
            for (int r = 0; r < 4; r++) {
                const int m  = bm * 128 + wm * 64 + i * 16 + l4 * 4 + r;
                const int bi = m >> 11, t = m & 2047;
                const int bh = bi * NH + h;
                const float v = (acc[i][j][r] + bv[j]) * qs;
                size_t idx;
                if (which == 2)
                    idx = 2 * (size_t)WS_STRIDE + ((size_t)bh * D_HEAD + d) * T_SEQ + t;
                else
                    idx = (size_t)which * WS_STRIDE + ((size_t)bh * T_SEQ + t) * D_HEAD + d;
                ws[idx] = (__bf16)v;
            }
        }
    }
}

// ---------------------------------------------------------------------------
// Kernel 2: causal ReLU attention v10 (unchanged this round).
// ---------------------------------------------------------------------------
#define KSTAGE(jt_, p_) {                                                     \
    _Pragma("unroll")                                                         \
    for (int e_ = 0; e_ < 4; e_++) {                                          \
        const int rb_ = w * 32 + e_ * 8;                                      \
        gl_lds16(kg + (size_t)((jt_) * 128 + rb_ + ksub) * 64                 \
                    + ((kc ^ ksub ^ (e_ << 1)) * 8),                          \
                 &Kb[p_][rb_ * 64]);                                          \
    }                                                                         \
}

#define VSTAGE(jt_) {                                                         \
    _Pragma("unroll")                                                         \
    for (int e_ = 0; e_ < 4; e_++) {                                          \
        const int rb_ = w * 16 + e_ * 4;                                      \
        const int sw_ = (rb_ & 12) + vsub;   /* == (row & 15) */              \
        gl_lds16(vt + (size_t)(rb_ + vsub) * T_SEQ + (jt_) * 128              \
                    + ((vc ^ sw_) * 8),                                       \
                 &Vts[rb_ * 128]);                                            \
    }                                                                         \
}

__global__ __launch_bounds__(256) void attn(
    const bf16* __restrict__ ws, float* __restrict__ out)
{
    __shared__ bf16 Kb[2][128 * 64];   // [key][d], chunk ^ (r&7) ^ ((r>>3)&3)<<1
    __shared__ bf16 Vts[64 * 128];     // [d][key], 16-chunk XOR swizzle

    const int tid  = threadIdx.x;
    const int lane = tid & 63;
    const int w    = tid >> 6;           // 0..3
    const int l15  = lane & 15, qd = lane >> 4;

    const int bh = blockIdx.x & 31;      // XCD = blk&7 -> bh mod 8 affinity
    const int u  = blockIdx.x >> 5;      // 0..31
    const int s  = 31 - u;               // big q-slices dispatch first
    const int qt = s >> 1;               // q-tile 0..15
    const int hs = s & 1;                // half within q-tile
    const int nj = qt + 1;
    const int qb = s * 64;               // block q-row base

    const bf16* qg = ws + (size_t)bh * (T_SEQ * D_HEAD);
    const bf16* kg = ws + WS_STRIDE + (size_t)bh * (T_SEQ * D_HEAD);
    const bf16* vt = ws + 2 * (size_t)WS_STRIDE + (size_t)bh * (D_HEAD * T_SEQ);
    const int b = bh >> 4, h = bh & 15;

    // staging lane constants
    const int ksub = lane >> 3;          // K: row-in-issue 0..7
    const int kc   = lane & 7;           // K: stored chunk position
    const int vsub = qd;                 // V: row-in-issue 0..3
    const int vc   = l15;                // V: stored chunk position

    // K fragment-read lane constants (conflict-free positions)
    const int krow0 = 8 * (l15 >> 2) + (l15 & 3);                  // row base
    const int pos00 = qd ^ (l15 & 3) ^ ((l15 >> 2) << 1);          // 0..7
    const int kbO0  = krow0 * 64 + pos00 * 8;
    const int kbO1  = krow0 * 64 + (pos00 ^ 4) * 8;

    // Q fragments (pre-scaled by 1/8), live across whole loop
    bf16x8 qF[2];
#pragma unroll
    for (int dk = 0; dk < 2; dk++)
        qF[dk] = *(const bf16x8*)(qg
            + (qb + w * 16 + l15) * 64 + dk * 32 + qd * 8);

    f32x4 o[4];
#pragma unroll
    for (int sd = 0; sd < 4; sd++) o[sd] = (f32x4){0.f, 0.f, 0.f, 0.f};

    // ---- prologue: stage K tile 0 into buffer 0 ----
    KSTAGE(0, 0);

    for (int jt = 0; jt < nj; ++jt) {
        const int p = jt & 1;
        const bool more = (jt + 1 < nj);
        // V(jt) first (mid-step counted wait retires it), then K(jt+1).
        VSTAGE(jt);
        if (more) {
            KSTAGE(jt + 1, p ^ 1);
            asm volatile("s_waitcnt vmcnt(8)" ::: "memory");  // K(jt) landed
        } else {
            asm volatile("s_waitcnt vmcnt(4)" ::: "memory");  // K(jt) landed
        }
        BAR;   // K tile jt visible to all waves

        const bf16* kb0 = &Kb[p][kbO0];
        const bf16* kb1 = &Kb[p][kbO1];

        // ---- QK (permuted rows) + relu + mask + pack ----
        const bool need_mask = (jt == nj - 1);
        // diagonal tile, even half-slice: keys >= qt*128+64 fully masked
        const int mMax = (need_mask && hs == 0) ? 2 : 4;
        unsigned PK[8][2];
#pragma unroll
        for (int m = 0; m < 4; m++) {
            if (m < mMax) {
                bf16x8 kf[2][2];
                kf[0][0] = *(const bf16x8*)(kb0 + m * 2048);        // kn=2m, lo
                kf[0][1] = *(const bf16x8*)(kb1 + m * 2048);        // kn=2m, hi
                kf[1][0] = *(const bf16x8*)(kb1 + m * 2048 + 256);  // kn=2m+1, lo
                kf[1][1] = *(const bf16x8*)(kb0 + m * 2048 + 256);  // kn=2m+1, hi
#pragma unroll
                for (int h2 = 0; h2 < 2; h2++) {
                    const int kn = 2 * m + h2;
                    f32x4 s0 = {0.f, 0.f, 0.f, 0.f};
                    __builtin_amdgcn_s_setprio(1);
                    s0 = __builtin_amdgcn_mfma_f32_16x16x32_bf16(kf[h2][0], qF[0], s0, 0, 0, 0);
                    s0 = __builtin_amdgcn_mfma_f32_16x16x32_bf16(kf[h2][1], qF[1], s0, 0, 0, 0);
                    __builtin_amdgcn_s_setprio(0);
                    const int keyb = jt * 128 + 32 * m + 8 * qd + 4 * h2;
                    float v[4];
#pragma unroll
                    for (int r = 0; r < 4; r++) v[r] = fmaxf(s0[r], 0.f);
                    if (need_mask) {   // wave-uniform: last step only
                        const int q = qb + w * 16 + l15;
#pragma unroll
                        for (int r = 0; r < 4; r++)
                            if (q < keyb + r) v[r] = 0.f;
                    }
                    PK[kn][0] = pack_bf16(v[0], v[1]);
                    PK[kn][1] = pack_bf16(v[2], v[3]);
                }
            }
        }

        // V landed under QK; counted wait keeps K(jt+1) in flight
        if (more) asm volatile("s_waitcnt vmcnt(4)" ::: "memory");
        else      asm volatile("s_waitcnt vmcnt(0)" ::: "memory");
        BAR;   // V tile jt visible to all waves

        // ---- PV: pF direct from this lane's PK dwords; vF from LDS ----
#pragma unroll
        for (int kk = 0; kk < 4; kk++) {
            if (kk < mMax) {
                union { unsigned dw[4]; bf16x8 v; } uu;
                uu.dw[0] = PK[2 * kk + 0][0];
                uu.dw[1] = PK[2 * kk + 0][1];
                uu.dw[2] = PK[2 * kk + 1][0];
                uu.dw[3] = PK[2 * kk + 1][1];
                const bf16x8 pF = uu.v;
                __builtin_amdgcn_s_setprio(1);
#pragma unroll
                for (int sd = 0; sd < 4; sd++) {
                    bf16x8 vf = *(const bf16x8*)&Vts[(sd * 16 + l15) * 128
                                                     + (((kk * 4 + qd) ^ l15) * 8)];
                    o[sd] = __builtin_amdgcn_mfma_f32_16x16x32_bf16(pF, vf, o[sd], 0, 0, 0);
                }
                __builtin_amdgcn_s_setprio(0);
            }
        }

        BAR;   // WAR: next step's V/K staging overwrites buffers just read
    }

    // ---- plain-store O (exclusive q-row ownership) ----
#pragma unroll
    for (int sd = 0; sd < 4; sd++) {
        const int d = sd * 16 + l15;
#pragma unroll
        for (int r = 0; r < 4; r++) {
            const int t = qb + w * 16 + qd * 4 + r;
            out[((size_t)b * T_SEQ + t) * C_EMB + h * 64 + d] = o[sd][r];
        }
    }
}

extern "C" void kernel_launch(void* const* d_in, const int* in_sizes, int n_in,
                              void* d_out, int out_size, void* d_ws, size_t ws_size,
                              hipStream_t stream) {
    const float* x    = (const float*)d_in[0];
    const float* W    = (const float*)d_in[1];
    const float* bias = (const float*)d_in[2];
    float* out        = (float*)d_out;
    bf16*  ws         = (bf16*)d_ws;

    if (ws_size >= WS_NEEDED) {
        bf16* xb = ws + 3 * (size_t)WS_STRIDE;
        bf16* wb = xb + XN;
        cvt_bf16<<<dim3(CVT_GRID), dim3(256), 0, stream>>>(x, W, xb, wb);
        qkv_gemm5<<<dim3(512), dim3(256), 0, stream>>>(xb, wb, bias, ws);
    } else {
        qkv_gemm<<<dim3(768), dim3(256), 0, stream>>>(x, W, bias, ws);
    }
    attn<<<dim3(1024), dim3(256), 0, stream>>>(ws, out);
}